// Round 12
// baseline (2243.592 us; speedup 1.0000x reference)
//
#include <hip/hip_runtime.h>

// VectorQuantizer: B=32768, K=8192, D=256, fp32.
// out layout (flat float): z_q [B*D], vq_loss [1], commit [1], indices-as-float [B]
// ws layout: idx_i int[B] | s_z float[B] | partial float[B/4]
//
// Numerics (verified round 2): ref dist = fl32(S - 2*fl32(dot)), dot = single
// fp32 FMA chain ascending in d per (row,code); frequent exact ties resolved
// by FIRST index. fmaf(-2,acc,S) == fl(S - 2*dot) exactly.
//
// Measured laws:
//  - VGPR cap: 128 @512thr, 256 @256thr/(256,1). Spill shows as WRITE_SIZE MBs.
//  - LDS co-residency: granule ~32KB, pool ~128-160KB (80KB->1 blk, 48KB->2).
//  - LDS throughput: dense ds_read_b128 ~12cyc/wave (85 B/cyc/CU); same-addr
//    b128 broadcast ~free. r9's 8x8 tile was LDS-BOUND (1280 LDS vs 1120 VALU
//    cyc per dk per CU) -> 65% VALU ceiling. r11's readlane za traded LDS for
//    +28% VALU-active. Fix: raise FMA:eb ratio.
//
// Round-12: 8 rows x 16 codes/thread. eb = 0.5 B/FMA -> ~80 B/cyc LDS demand
// at full FMA rate (just under the 85 limit); za broadcast free. 256-thr
// blocks (4 waves), BM=32, BN=1024: zT 32KB + eT 32KB = 64KB -> 2 blocks/CU
// = 8 waves/CU in TWO INDEPENDENT barrier groups (mutual stall-filling,
// unlike r9's single lockstep 8-wave group). VGPR ~225 <= 256 cap.

namespace {
constexpr int NB = 32768;
constexpr int NK = 8192;
constexpr int ND = 256;
constexpr int BM = 32;    // rows per block (4 waves x 8 rows)
constexpr int BN = 1024;  // codes per chunk
constexpr int BK = 4;     // d per stage
constexpr int NT = 256;   // threads per block (4 waves)

// ---- S[row] = ||z_row||^2 ----
__global__ void sz_kernel(const float* __restrict__ z, float* __restrict__ sz) {
  const int row = blockIdx.x * 4 + (threadIdx.x >> 6);
  const int lane = threadIdx.x & 63;
  const float4 v = reinterpret_cast<const float4*>(z)[(size_t)row * (ND / 4) + lane];
  float s = v.x * v.x + v.y * v.y + v.z * v.z + v.w * v.w;
#pragma unroll
  for (int off = 32; off; off >>= 1) s += __shfl_down(s, off, 64);
  if (lane == 0) sz[row] = s;
}

// ---- argmin over codes of fl32(S - 2*fl32(z.e)), first-index tie-break ----
__global__ __launch_bounds__(NT, 1) void argmin_kernel(
    const float* __restrict__ z, const float* __restrict__ emb,
    const float* __restrict__ sz, int* __restrict__ idx_i,
    float* __restrict__ idx_f) {
  __shared__ float zT[ND][BM];       // 32 KB, persistent z^T tile
  __shared__ float eT[2][BK][BN];    // 32 KB, double-buffered e^T chunk

  const int tid = threadIdx.x;
  const int tx = tid & 63;   // code lane (full wave)
  const int ty = tid >> 6;   // wave id = row group (0..3), wave-uniform
  const int ty8 = ty * 8;
  const int row0 = blockIdx.x * BM;

  // stage zT (transpose z[row][d] -> zT[d][row]); coalesced, one-time
  {
    const float4* z4 = reinterpret_cast<const float4*>(z) + (size_t)row0 * 64;
#pragma unroll
    for (int it = 0; it < 8; ++it) {
      int fi = it * NT + tid;  // float4 index in tile (32 rows * 64 f4/row)
      int r = fi >> 6;
      int dq = fi & 63;
      float4 v = z4[(size_t)r * 64 + dq];
      zT[dq * 4 + 0][r] = v.x;
      zT[dq * 4 + 1][r] = v.y;
      zT[dq * 4 + 2][r] = v.z;
      zT[dq * 4 + 3][r] = v.w;
    }
  }
  // first zT read happens after the first in-loop __syncthreads()

  float best[8];
  int bidx[8];
#pragma unroll
  for (int i = 0; i < 8; ++i) { best[i] = 3.4e38f; bidx[i] = 0; }

  const float4* e4 = reinterpret_cast<const float4*>(emb);

  float eb[2][16];
  auto leb = [&](int b, int buf, int dd) {
#pragma unroll
    for (int m = 0; m < 4; ++m) {
      const float4 e =
          *reinterpret_cast<const float4*>(&eT[buf][dd][m * 256 + tx * 4]);
      eb[b][m * 4 + 0] = e.x;
      eb[b][m * 4 + 1] = e.y;
      eb[b][m * 4 + 2] = e.z;
      eb[b][m * 4 + 3] = e.w;
    }
  };

  for (int n = 0; n < NK / BN; ++n) {  // 8 chunks
    const int c0 = n * BN;
    float acc[8][16];
#pragma unroll
    for (int i = 0; i < 8; ++i)
#pragma unroll
      for (int j = 0; j < 16; ++j) acc[i][j] = 0.f;

    // preload dk=0 slice: thread stages codes c0+tid+{0,256,512,768}
    float4 p0 = e4[(size_t)(c0 + tid) * 64];
    float4 p1 = e4[(size_t)(c0 + tid + 256) * 64];
    float4 p2 = e4[(size_t)(c0 + tid + 512) * 64];
    float4 p3 = e4[(size_t)(c0 + tid + 768) * 64];

    for (int dk = 0; dk < ND / BK; ++dk) {  // 64 stages
      const int buf = dk & 1;
      // transposed store eT[dd][code]; lane-consecutive -> conflict-free
      eT[buf][0][tid] = p0.x;
      eT[buf][1][tid] = p0.y;
      eT[buf][2][tid] = p0.z;
      eT[buf][3][tid] = p0.w;
      eT[buf][0][tid + 256] = p1.x;
      eT[buf][1][tid + 256] = p1.y;
      eT[buf][2][tid + 256] = p1.z;
      eT[buf][3][tid + 256] = p1.w;
      eT[buf][0][tid + 512] = p2.x;
      eT[buf][1][tid + 512] = p2.y;
      eT[buf][2][tid + 512] = p2.z;
      eT[buf][3][tid + 512] = p2.w;
      eT[buf][0][tid + 768] = p3.x;
      eT[buf][1][tid + 768] = p3.y;
      eT[buf][2][tid + 768] = p3.z;
      eT[buf][3][tid + 768] = p3.w;
      if (dk + 1 < ND / BK) {  // prefetch next slice (L2/L3-served)
        p0 = e4[(size_t)(c0 + tid) * 64 + dk + 1];
        p1 = e4[(size_t)(c0 + tid + 256) * 64 + dk + 1];
        p2 = e4[(size_t)(c0 + tid + 512) * 64 + dk + 1];
        p3 = e4[(size_t)(c0 + tid + 768) * 64 + dk + 1];
      }
      __syncthreads();  // dbuf: single barrier per stage
      leb(0, buf, 0);
#pragma unroll
      for (int dd = 0; dd < BK; ++dd) {
        const int cur = dd & 1;
        if (dd < BK - 1) leb(cur ^ 1, buf, dd + 1);  // prefetch next dd's eb
        const int d = dk * BK + dd;
        // za: one address per wave (ty uniform) -> free broadcast b128 reads
        const float4 a0 = *reinterpret_cast<const float4*>(&zT[d][ty8]);
        const float4 a1 = *reinterpret_cast<const float4*>(&zT[d][ty8 + 4]);
        const float za[8] = {a0.x, a0.y, a0.z, a0.w, a1.x, a1.y, a1.z, a1.w};
        // single fp32 FMA chain per (row, code), ascending d
#pragma unroll
        for (int i = 0; i < 8; ++i)
#pragma unroll
          for (int j = 0; j < 16; ++j)
            acc[i][j] = fmaf(za[i], eb[cur][j], acc[i][j]);
      }
    }

    // running argmin: dist = fl32(S - 2*fl32(dot)); ascending code order
#pragma unroll
    for (int i = 0; i < 8; ++i) {
      const float S = sz[row0 + ty8 + i];  // wave-uniform, cache-hot
#pragma unroll
      for (int m = 0; m < 4; ++m)
#pragma unroll
        for (int s = 0; s < 4; ++s) {
          const float dist = fmaf(-2.0f, acc[i][m * 4 + s], S);
          const int code = c0 + m * 256 + tx * 4 + s;
          if (dist < best[i]) {  // strict <: earliest index wins
            best[i] = dist;
            bidx[i] = code;
          }
        }
    }
  }

  // full-wave (64 lane) reduce; prefer smaller index on exact ties
#pragma unroll
  for (int i = 0; i < 8; ++i) {
    float bv = best[i];
    int bi = bidx[i];
#pragma unroll
    for (int m = 1; m < 64; m <<= 1) {
      float ov = __shfl_xor(bv, m, 64);
      int oi = __shfl_xor(bi, m, 64);
      if (ov < bv || (ov == bv && oi < bi)) { bv = ov; bi = oi; }
    }
    if (tx == 0) {
      int row = row0 + ty8 + i;
      idx_i[row] = bi;
      idx_f[row] = (float)bi;
    }
  }
}

// ---- gather z_q = emb[idx], partial sums of (z_q - z)^2 ----
__global__ void gather_kernel(const float* __restrict__ z,
                              const float* __restrict__ emb,
                              const int* __restrict__ idx,
                              float* __restrict__ zq,
                              float* __restrict__ partial) {
  const int w = threadIdx.x >> 6;
  const int lane = threadIdx.x & 63;
  const int row = blockIdx.x * 4 + w;
  const int k = idx[row];
  const float4 e = reinterpret_cast<const float4*>(emb)[(size_t)k * (ND / 4) + lane];
  const float4 zv = reinterpret_cast<const float4*>(z)[(size_t)row * (ND / 4) + lane];
  reinterpret_cast<float4*>(zq)[(size_t)row * (ND / 4) + lane] = e;
  const float dx = e.x - zv.x, dy = e.y - zv.y, dz = e.z - zv.z, dw = e.w - zv.w;
  float s = dx * dx + dy * dy + dz * dz + dw * dw;
#pragma unroll
  for (int off = 32; off; off >>= 1) s += __shfl_down(s, off, 64);
  __shared__ float sm[4];
  if (lane == 0) sm[w] = s;
  __syncthreads();
  if (threadIdx.x == 0) partial[blockIdx.x] = sm[0] + sm[1] + sm[2] + sm[3];
}

// ---- deterministic final loss reduction ----
__global__ void loss_kernel(const float* __restrict__ partial, int n,
                            float* __restrict__ out_loss) {
  double s = 0.0;
  for (int i = threadIdx.x; i < n; i += 256) s += (double)partial[i];
  __shared__ double sm[256];
  sm[threadIdx.x] = s;
  __syncthreads();
  for (int st = 128; st; st >>= 1) {
    if (threadIdx.x < st) sm[threadIdx.x] += sm[threadIdx.x + st];
    __syncthreads();
  }
  if (threadIdx.x == 0) {
    float loss = (float)(0.25 * sm[0] / (double)((size_t)NB * ND));
    out_loss[0] = loss;  // vq_loss
    out_loss[1] = loss;  // commitment loss (same forward value)
  }
}

}  // namespace

extern "C" void kernel_launch(void* const* d_in, const int* in_sizes, int n_in,
                              void* d_out, int out_size, void* d_ws, size_t ws_size,
                              hipStream_t stream) {
  const float* z = (const float*)d_in[0];
  const float* emb = (const float*)d_in[1];
  float* out = (float*)d_out;
  float* zq = out;
  float* loss = out + (size_t)NB * ND;
  float* idx_f = out + (size_t)NB * ND + 2;

  int* idx_i = (int*)d_ws;
  float* sz = (float*)((char*)d_ws + (size_t)NB * 4);
  float* partial = (float*)((char*)d_ws + (size_t)NB * 4 * 2);

  sz_kernel<<<NB / 4, 256, 0, stream>>>(z, sz);
  argmin_kernel<<<NB / BM, NT, 0, stream>>>(z, emb, sz, idx_i, idx_f);
  gather_kernel<<<NB / 4, 256, 0, stream>>>(z, emb, idx_i, zq, partial);
  loss_kernel<<<1, 256, 0, stream>>>(partial, NB / 4, loss);
}

// Round 13
// 2126.506 us; speedup vs baseline: 1.0551x; 1.0551x over previous
//
#include <hip/hip_runtime.h>

// VectorQuantizer: B=32768, K=8192, D=256, fp32.
// out layout (flat float): z_q [B*D], vq_loss [1], commit [1], indices-as-float [B]
// ws layout: idx_i int[B] | s_z float[B] | partial float[B/4]
//
// Numerics (verified round 2): ref dist = fl32(S - 2*fl32(dot)), dot = single
// fp32 FMA chain ascending in d per (row,code); frequent exact ties resolved
// by FIRST index. fmaf(-2,acc,S) == fl(S - 2*dot) exactly.
//
// Measured laws (r2-r12):
//  - VGPR: allocator comfort ceiling ~152 @256thr; beyond -> silent AGPR
//    shuffling (VALU bloat, no scratch traffic). Keep arch need <= ~140.
//  - LDS pool: ~128KB usable. 2x48KB co-resides (r10); 2x64KB does NOT (r12).
//  - LDS throughput: dense ds_read_b128 ~12cyc/wave; need >=8 rows/thread or
//    eb reads bind before VALU (r10). Broadcast (wave-uniform addr) ~free.
//  - Single 8-wave lockstep block: barrier+ds latency exposed -> 65% VALU (r9).
//
// Round-13 = r9 economics in TWO independent 4-wave blocks:
//   NT=256 (4 waves), BM=32 (8 rows/wave), BN=512, BK=4, tile 8x8, acc=64.
//   zT 32KB + eT[2][4][512] 16KB = 48KB -> 2 blocks/CU = 8 waves/CU in two
//   independent barrier groups (mutual stall filling). VGPR ~130 < 152.

namespace {
constexpr int NB = 32768;
constexpr int NK = 8192;
constexpr int ND = 256;
constexpr int BM = 32;    // rows per block (4 waves x 8 rows)
constexpr int BN = 512;   // codes per chunk
constexpr int BK = 4;     // d per stage
constexpr int NT = 256;   // threads per block (4 waves)

// ---- S[row] = ||z_row||^2 ----
__global__ void sz_kernel(const float* __restrict__ z, float* __restrict__ sz) {
  const int row = blockIdx.x * 4 + (threadIdx.x >> 6);
  const int lane = threadIdx.x & 63;
  const float4 v = reinterpret_cast<const float4*>(z)[(size_t)row * (ND / 4) + lane];
  float s = v.x * v.x + v.y * v.y + v.z * v.z + v.w * v.w;
#pragma unroll
  for (int off = 32; off; off >>= 1) s += __shfl_down(s, off, 64);
  if (lane == 0) sz[row] = s;
}

// ---- argmin over codes of fl32(S - 2*fl32(z.e)), first-index tie-break ----
__global__ __launch_bounds__(NT, 1) void argmin_kernel(
    const float* __restrict__ z, const float* __restrict__ emb,
    const float* __restrict__ sz, int* __restrict__ idx_i,
    float* __restrict__ idx_f) {
  __shared__ float zT[ND][BM];       // 32 KB, persistent z^T tile
  __shared__ float eT[2][BK][BN];    // 16 KB, double-buffered e^T chunk

  const int tid = threadIdx.x;
  const int tx = tid & 63;   // code lane (full wave)
  const int ty = tid >> 6;   // wave id = row group (0..3), wave-uniform
  const int ty8 = ty * 8;
  const int row0 = blockIdx.x * BM;

  // stage zT (transpose z[row][d] -> zT[d][row]); coalesced, one-time
  {
    const float4* z4 = reinterpret_cast<const float4*>(z) + (size_t)row0 * 64;
#pragma unroll
    for (int it = 0; it < 8; ++it) {
      int fi = it * NT + tid;  // float4 index in tile (32 rows * 64 f4/row)
      int r = fi >> 6;
      int dq = fi & 63;
      float4 v = z4[(size_t)r * 64 + dq];
      zT[dq * 4 + 0][r] = v.x;
      zT[dq * 4 + 1][r] = v.y;
      zT[dq * 4 + 2][r] = v.z;
      zT[dq * 4 + 3][r] = v.w;
    }
  }
  // first zT read happens after the first in-loop __syncthreads()

  float best[8];
  int bidx[8];
#pragma unroll
  for (int i = 0; i < 8; ++i) { best[i] = 3.4e38f; bidx[i] = 0; }

  const float4* e4 = reinterpret_cast<const float4*>(emb);
  const int cA = tid;        // stages code rows tid and tid+256
  const int cB = tid + 256;

  float eb[2][8];
  auto leb = [&](int b, int buf, int dd) {
    const float4 e0 = *reinterpret_cast<const float4*>(&eT[buf][dd][tx * 4]);
    const float4 e1 = *reinterpret_cast<const float4*>(&eT[buf][dd][256 + tx * 4]);
    eb[b][0] = e0.x; eb[b][1] = e0.y; eb[b][2] = e0.z; eb[b][3] = e0.w;
    eb[b][4] = e1.x; eb[b][5] = e1.y; eb[b][6] = e1.z; eb[b][7] = e1.w;
  };

  for (int n = 0; n < NK / BN; ++n) {  // 16 chunks
    const int c0 = n * BN;
    float acc[8][8];
#pragma unroll
    for (int i = 0; i < 8; ++i)
#pragma unroll
      for (int j = 0; j < 8; ++j) acc[i][j] = 0.f;

    // preload dk=0 slice (1 float4 = 4 d-values per staged code)
    float4 p0 = e4[(size_t)(c0 + cA) * 64 + 0];
    float4 p1 = e4[(size_t)(c0 + cB) * 64 + 0];

    for (int dk = 0; dk < ND / BK; ++dk) {  // 64 stages
      const int buf = dk & 1;
      // transposed store eT[dd][code]; lane-consecutive -> conflict-free
      eT[buf][0][cA] = p0.x;
      eT[buf][1][cA] = p0.y;
      eT[buf][2][cA] = p0.z;
      eT[buf][3][cA] = p0.w;
      eT[buf][0][cB] = p1.x;
      eT[buf][1][cB] = p1.y;
      eT[buf][2][cB] = p1.z;
      eT[buf][3][cB] = p1.w;
      if (dk + 1 < ND / BK) {  // prefetch next slice (L2/L3-served)
        p0 = e4[(size_t)(c0 + cA) * 64 + dk + 1];
        p1 = e4[(size_t)(c0 + cB) * 64 + dk + 1];
      }
      __syncthreads();  // dbuf: single barrier per stage
      leb(0, buf, 0);
#pragma unroll
      for (int dd = 0; dd < BK; ++dd) {
        const int cur = dd & 1;
        if (dd < BK - 1) leb(cur ^ 1, buf, dd + 1);  // prefetch next dd's eb
        const int d = dk * BK + dd;
        // za: one address per wave (ty uniform) -> free broadcast b128 reads
        const float4 a0 = *reinterpret_cast<const float4*>(&zT[d][ty8]);
        const float4 a1 = *reinterpret_cast<const float4*>(&zT[d][ty8 + 4]);
        const float za[8] = {a0.x, a0.y, a0.z, a0.w, a1.x, a1.y, a1.z, a1.w};
        // single fp32 FMA chain per (row, code), ascending d
#pragma unroll
        for (int i = 0; i < 8; ++i)
#pragma unroll
          for (int j = 0; j < 8; ++j)
            acc[i][j] = fmaf(za[i], eb[cur][j], acc[i][j]);
      }
    }

    // running argmin: dist = fl32(S - 2*fl32(dot)); ascending code order
#pragma unroll
    for (int i = 0; i < 8; ++i) {
      const float S = sz[row0 + ty8 + i];  // wave-uniform, cache-hot
#pragma unroll
      for (int m = 0; m < 2; ++m)
#pragma unroll
        for (int s = 0; s < 4; ++s) {
          const float dist = fmaf(-2.0f, acc[i][m * 4 + s], S);
          const int code = c0 + m * 256 + tx * 4 + s;
          if (dist < best[i]) {  // strict <: earliest index wins
            best[i] = dist;
            bidx[i] = code;
          }
        }
    }
  }

  // full-wave (64 lane) reduce; prefer smaller index on exact ties
#pragma unroll
  for (int i = 0; i < 8; ++i) {
    float bv = best[i];
    int bi = bidx[i];
#pragma unroll
    for (int m = 1; m < 64; m <<= 1) {
      float ov = __shfl_xor(bv, m, 64);
      int oi = __shfl_xor(bi, m, 64);
      if (ov < bv || (ov == bv && oi < bi)) { bv = ov; bi = oi; }
    }
    if (tx == 0) {
      int row = row0 + ty8 + i;
      idx_i[row] = bi;
      idx_f[row] = (float)bi;
    }
  }
}

// ---- gather z_q = emb[idx], partial sums of (z_q - z)^2 ----
__global__ void gather_kernel(const float* __restrict__ z,
                              const float* __restrict__ emb,
                              const int* __restrict__ idx,
                              float* __restrict__ zq,
                              float* __restrict__ partial) {
  const int w = threadIdx.x >> 6;
  const int lane = threadIdx.x & 63;
  const int row = blockIdx.x * 4 + w;
  const int k = idx[row];
  const float4 e = reinterpret_cast<const float4*>(emb)[(size_t)k * (ND / 4) + lane];
  const float4 zv = reinterpret_cast<const float4*>(z)[(size_t)row * (ND / 4) + lane];
  reinterpret_cast<float4*>(zq)[(size_t)row * (ND / 4) + lane] = e;
  const float dx = e.x - zv.x, dy = e.y - zv.y, dz = e.z - zv.z, dw = e.w - zv.w;
  float s = dx * dx + dy * dy + dz * dz + dw * dw;
#pragma unroll
  for (int off = 32; off; off >>= 1) s += __shfl_down(s, off, 64);
  __shared__ float sm[4];
  if (lane == 0) sm[w] = s;
  __syncthreads();
  if (threadIdx.x == 0) partial[blockIdx.x] = sm[0] + sm[1] + sm[2] + sm[3];
}

// ---- deterministic final loss reduction ----
__global__ void loss_kernel(const float* __restrict__ partial, int n,
                            float* __restrict__ out_loss) {
  double s = 0.0;
  for (int i = threadIdx.x; i < n; i += 256) s += (double)partial[i];
  __shared__ double sm[256];
  sm[threadIdx.x] = s;
  __syncthreads();
  for (int st = 128; st; st >>= 1) {
    if (threadIdx.x < st) sm[threadIdx.x] += sm[threadIdx.x + st];
    __syncthreads();
  }
  if (threadIdx.x == 0) {
    float loss = (float)(0.25 * sm[0] / (double)((size_t)NB * ND));
    out_loss[0] = loss;  // vq_loss
    out_loss[1] = loss;  // commitment loss (same forward value)
  }
}

}  // namespace

extern "C" void kernel_launch(void* const* d_in, const int* in_sizes, int n_in,
                              void* d_out, int out_size, void* d_ws, size_t ws_size,
                              hipStream_t stream) {
  const float* z = (const float*)d_in[0];
  const float* emb = (const float*)d_in[1];
  float* out = (float*)d_out;
  float* zq = out;
  float* loss = out + (size_t)NB * ND;
  float* idx_f = out + (size_t)NB * ND + 2;

  int* idx_i = (int*)d_ws;
  float* sz = (float*)((char*)d_ws + (size_t)NB * 4);
  float* partial = (float*)((char*)d_ws + (size_t)NB * 4 * 2);

  sz_kernel<<<NB / 4, 256, 0, stream>>>(z, sz);
  argmin_kernel<<<NB / BM, NT, 0, stream>>>(z, emb, sz, idx_i, idx_f);
  gather_kernel<<<NB / 4, 256, 0, stream>>>(z, emb, idx_i, zq, partial);
  loss_kernel<<<1, 256, 0, stream>>>(partial, NB / 4, loss);
}

// Round 14
// 1612.734 us; speedup vs baseline: 1.3912x; 1.3186x over previous
//
#include <hip/hip_runtime.h>

// VectorQuantizer: B=32768, K=8192, D=256, fp32.
// out layout (flat float): z_q [B*D], vq_loss [1], commit [1], indices-as-float [B]
// ws layout: idx_i int[B] | s_z float[B] | partial float[B/4]
//
// Numerics (verified round 2): ref dist = fl32(S - 2*fl32(dot)), dot = single
// fp32 FMA chain ascending in d per (row,code); frequent exact ties resolved
// by FIRST index. fmaf(-2,acc,S) == fl(S - 2*dot) exactly.
//
// Measured laws (r2-r13):
//  - VGPR cap 128 @512thr, comfort ~152 @256thr. Spill => WRITE_SIZE in MBs.
//  - LDS pool ~96-127KB usable: 2x48KB ok (r10/r13), 2x64KB NOT (r12), 96KB
//    single block ok (r8).
//  - VALU-active for this algorithm ~1260us (FMA 874 + ~30% overhead).
//  - Stall ~800 cyc PER BARRIER-ITERATION, topology-independent (r9 vs r13:
//    same per-iter stall, r13 had 2x iters -> 2x stall). Independent blocks
//    do NOT de-phase. Lever: fewer, fatter iterations.
//
// Round-14 = r9 with BK=8 (fat stages):
//   512 threads (8 waves), BM=64, BN=512, BK=8, tile 8x8, acc=64.
//   LDS: zT 64KB + eT[2][8][512] 32KB = 96KB -> 1 block/CU, 8 waves.
//   Barrier-iters/CU: 2 passes x 16 chunks x 32 = 1024 (half of r9).
//   Per iter: 512 FMA/thread = 2048 cyc issue/SIMD vs ~800 stall -> ~72% duty.
//   Thread stages its one code row: 2 float4 = d (dk*8..+7). VGPR ~112 < 128.

namespace {
constexpr int NB = 32768;
constexpr int NK = 8192;
constexpr int ND = 256;
constexpr int BM = 64;    // rows per block (8 waves x 8 rows)
constexpr int BN = 512;   // codes per chunk
constexpr int BK = 8;     // d per stage
constexpr int NT = 512;   // threads per block (8 waves)

// ---- S[row] = ||z_row||^2 ----
__global__ void sz_kernel(const float* __restrict__ z, float* __restrict__ sz) {
  const int row = blockIdx.x * 4 + (threadIdx.x >> 6);
  const int lane = threadIdx.x & 63;
  const float4 v = reinterpret_cast<const float4*>(z)[(size_t)row * (ND / 4) + lane];
  float s = v.x * v.x + v.y * v.y + v.z * v.z + v.w * v.w;
#pragma unroll
  for (int off = 32; off; off >>= 1) s += __shfl_down(s, off, 64);
  if (lane == 0) sz[row] = s;
}

// ---- argmin over codes of fl32(S - 2*fl32(z.e)), first-index tie-break ----
__global__ __launch_bounds__(NT, 1) void argmin_kernel(
    const float* __restrict__ z, const float* __restrict__ emb,
    const float* __restrict__ sz, int* __restrict__ idx_i,
    float* __restrict__ idx_f) {
  __shared__ float zT[ND][BM];       // 64 KB, persistent z^T tile
  __shared__ float eT[2][BK][BN];    // 32 KB, double-buffered e^T stage

  const int tid = threadIdx.x;
  const int tx = tid & 63;   // code lane (full wave)
  const int ty = tid >> 6;   // wave id = row group (0..7), wave-uniform
  const int ty8 = ty * 8;
  const int row0 = blockIdx.x * BM;

  // stage zT (transpose z[row][d] -> zT[d][row]); coalesced, one-time
  {
    const float4* z4 = reinterpret_cast<const float4*>(z) + (size_t)row0 * 64;
#pragma unroll
    for (int it = 0; it < 8; ++it) {
      int fi = it * NT + tid;  // float4 index in tile (64 rows * 64 f4/row)
      int r = fi >> 6;
      int dq = fi & 63;
      float4 v = z4[(size_t)r * 64 + dq];
      zT[dq * 4 + 0][r] = v.x;
      zT[dq * 4 + 1][r] = v.y;
      zT[dq * 4 + 2][r] = v.z;
      zT[dq * 4 + 3][r] = v.w;
    }
  }
  // first zT read happens after the first in-loop __syncthreads()

  float best[8];
  int bidx[8];
#pragma unroll
  for (int i = 0; i < 8; ++i) { best[i] = 3.4e38f; bidx[i] = 0; }

  const float4* e4 = reinterpret_cast<const float4*>(emb);

  float eb[2][8];
  auto leb = [&](int b, int buf, int dd) {
    const float4 e0 = *reinterpret_cast<const float4*>(&eT[buf][dd][tx * 4]);
    const float4 e1 = *reinterpret_cast<const float4*>(&eT[buf][dd][256 + tx * 4]);
    eb[b][0] = e0.x; eb[b][1] = e0.y; eb[b][2] = e0.z; eb[b][3] = e0.w;
    eb[b][4] = e1.x; eb[b][5] = e1.y; eb[b][6] = e1.z; eb[b][7] = e1.w;
  };

  for (int n = 0; n < NK / BN; ++n) {  // 16 chunks
    const int c0 = n * BN;
    float acc[8][8];
#pragma unroll
    for (int i = 0; i < 8; ++i)
#pragma unroll
      for (int j = 0; j < 8; ++j) acc[i][j] = 0.f;

    // thread owns code row c0+tid; stage 8 d per iter = 2 float4
    const float4* ecode = e4 + (size_t)(c0 + tid) * 64;
    float4 p0 = ecode[0];
    float4 p1 = ecode[1];

    for (int dk = 0; dk < ND / BK; ++dk) {  // 32 fat stages
      const int buf = dk & 1;
      // transposed store eT[dd][code]; all 512 lanes consecutive per dd
      eT[buf][0][tid] = p0.x;
      eT[buf][1][tid] = p0.y;
      eT[buf][2][tid] = p0.z;
      eT[buf][3][tid] = p0.w;
      eT[buf][4][tid] = p1.x;
      eT[buf][5][tid] = p1.y;
      eT[buf][6][tid] = p1.z;
      eT[buf][7][tid] = p1.w;
      if (dk + 1 < ND / BK) {  // prefetch next stage (2048-cyc window)
        p0 = ecode[(dk + 1) * 2];
        p1 = ecode[(dk + 1) * 2 + 1];
      }
      __syncthreads();  // dbuf: single barrier per stage
      leb(0, buf, 0);
#pragma unroll
      for (int dd = 0; dd < BK; ++dd) {
        const int cur = dd & 1;
        if (dd < BK - 1) leb(cur ^ 1, buf, dd + 1);  // prefetch next dd's eb
        const int d = dk * BK + dd;
        // za: one address per wave (ty uniform) -> free broadcast b128 reads
        const float4 a0 = *reinterpret_cast<const float4*>(&zT[d][ty8]);
        const float4 a1 = *reinterpret_cast<const float4*>(&zT[d][ty8 + 4]);
        const float za[8] = {a0.x, a0.y, a0.z, a0.w, a1.x, a1.y, a1.z, a1.w};
        // single fp32 FMA chain per (row, code), ascending d
#pragma unroll
        for (int i = 0; i < 8; ++i)
#pragma unroll
          for (int j = 0; j < 8; ++j)
            acc[i][j] = fmaf(za[i], eb[cur][j], acc[i][j]);
      }
    }

    // running argmin: dist = fl32(S - 2*fl32(dot)); ascending code order
#pragma unroll
    for (int i = 0; i < 8; ++i) {
      const float S = sz[row0 + ty8 + i];  // wave-uniform, cache-hot
#pragma unroll
      for (int m = 0; m < 2; ++m)
#pragma unroll
        for (int s = 0; s < 4; ++s) {
          const float dist = fmaf(-2.0f, acc[i][m * 4 + s], S);
          const int code = c0 + m * 256 + tx * 4 + s;
          if (dist < best[i]) {  // strict <: earliest index wins
            best[i] = dist;
            bidx[i] = code;
          }
        }
    }
  }

  // full-wave (64 lane) reduce; prefer smaller index on exact ties
#pragma unroll
  for (int i = 0; i < 8; ++i) {
    float bv = best[i];
    int bi = bidx[i];
#pragma unroll
    for (int m = 1; m < 64; m <<= 1) {
      float ov = __shfl_xor(bv, m, 64);
      int oi = __shfl_xor(bi, m, 64);
      if (ov < bv || (ov == bv && oi < bi)) { bv = ov; bi = oi; }
    }
    if (tx == 0) {
      int row = row0 + ty8 + i;
      idx_i[row] = bi;
      idx_f[row] = (float)bi;
    }
  }
}

// ---- gather z_q = emb[idx], partial sums of (z_q - z)^2 ----
__global__ void gather_kernel(const float* __restrict__ z,
                              const float* __restrict__ emb,
                              const int* __restrict__ idx,
                              float* __restrict__ zq,
                              float* __restrict__ partial) {
  const int w = threadIdx.x >> 6;
  const int lane = threadIdx.x & 63;
  const int row = blockIdx.x * 4 + w;
  const int k = idx[row];
  const float4 e = reinterpret_cast<const float4*>(emb)[(size_t)k * (ND / 4) + lane];
  const float4 zv = reinterpret_cast<const float4*>(z)[(size_t)row * (ND / 4) + lane];
  reinterpret_cast<float4*>(zq)[(size_t)row * (ND / 4) + lane] = e;
  const float dx = e.x - zv.x, dy = e.y - zv.y, dz = e.z - zv.z, dw = e.w - zv.w;
  float s = dx * dx + dy * dy + dz * dz + dw * dw;
#pragma unroll
  for (int off = 32; off; off >>= 1) s += __shfl_down(s, off, 64);
  __shared__ float sm[4];
  if (lane == 0) sm[w] = s;
  __syncthreads();
  if (threadIdx.x == 0) partial[blockIdx.x] = sm[0] + sm[1] + sm[2] + sm[3];
}

// ---- deterministic final loss reduction ----
__global__ void loss_kernel(const float* __restrict__ partial, int n,
                            float* __restrict__ out_loss) {
  double s = 0.0;
  for (int i = threadIdx.x; i < n; i += 256) s += (double)partial[i];
  __shared__ double sm[256];
  sm[threadIdx.x] = s;
  __syncthreads();
  for (int st = 128; st; st >>= 1) {
    if (threadIdx.x < st) sm[threadIdx.x] += sm[threadIdx.x + st];
    __syncthreads();
  }
  if (threadIdx.x == 0) {
    float loss = (float)(0.25 * sm[0] / (double)((size_t)NB * ND));
    out_loss[0] = loss;  // vq_loss
    out_loss[1] = loss;  // commitment loss (same forward value)
  }
}

}  // namespace

extern "C" void kernel_launch(void* const* d_in, const int* in_sizes, int n_in,
                              void* d_out, int out_size, void* d_ws, size_t ws_size,
                              hipStream_t stream) {
  const float* z = (const float*)d_in[0];
  const float* emb = (const float*)d_in[1];
  float* out = (float*)d_out;
  float* zq = out;
  float* loss = out + (size_t)NB * ND;
  float* idx_f = out + (size_t)NB * ND + 2;

  int* idx_i = (int*)d_ws;
  float* sz = (float*)((char*)d_ws + (size_t)NB * 4);
  float* partial = (float*)((char*)d_ws + (size_t)NB * 4 * 2);

  sz_kernel<<<NB / 4, 256, 0, stream>>>(z, sz);
  argmin_kernel<<<NB / BM, NT, 0, stream>>>(z, emb, sz, idx_i, idx_f);
  gather_kernel<<<NB / 4, 256, 0, stream>>>(z, emb, idx_i, zq, partial);
  loss_kernel<<<1, 256, 0, stream>>>(partial, NB / 4, loss);
}